// Round 1
// baseline (643.069 us; speedup 1.0000x reference)
//
#include <hip/hip_runtime.h>

typedef unsigned short u16;
typedef __attribute__((ext_vector_type(8))) short short8;
typedef __attribute__((ext_vector_type(4))) float f32x4;

#define DD 1024
#define NN 1024
#define MODS_LD 9216

__device__ __forceinline__ float bf2f(u16 v) {
  unsigned int u = ((unsigned int)v) << 16;
  return __builtin_bit_cast(float, u);
}
__device__ __forceinline__ u16 f2bf(float f) {
  unsigned int u = __builtin_bit_cast(unsigned int, f);
  unsigned int lsb = (u >> 16) & 1;
  u += 0x7fffu + lsb;
  return (u16)(u >> 16);
}

__device__ __forceinline__ void gload_lds16(const u16* g, u16* l) {
  __builtin_amdgcn_global_load_lds(
      (const __attribute__((address_space(1))) unsigned int*)g,
      (__attribute__((address_space(3))) unsigned int*)l, 16, 0, 0);
}

// ---------------- weight transpose + fp32->bf16 -------------------------
// src: R x C fp32 row-major. dst: C2 x R2 bf16 row-major, dst[c][r]=src[r][c], 0-padded.
__global__ void transpose_convert(const float* __restrict__ src, u16* __restrict__ dst,
                                  int R, int C, int R2, int C2) {
  __shared__ float tile[32][33];
  int tx = threadIdx.x, ty = threadIdx.y;
  int r0 = blockIdx.x * 32, c0 = blockIdx.y * 32;
#pragma unroll
  for (int i = 0; i < 4; ++i) {
    int r = r0 + ty + i * 8, c = c0 + tx;
    tile[ty + i * 8][tx] = (r < R && c < C) ? src[(long)r * C + c] : 0.f;
  }
  __syncthreads();
#pragma unroll
  for (int i = 0; i < 4; ++i) {
    int c = c0 + ty + i * 8, r = r0 + tx;
    if (c < C2 && r < R2) dst[(long)c * R2 + r] = f2bf(tile[tx][ty + i * 8]);
  }
}

// ---------------- fp32 -> bf16 (vector) ---------------------------------
__global__ void cvt_bf16_kernel(const float* __restrict__ in, u16* __restrict__ out, long n4) {
  long i = (long)blockIdx.x * 256 + threadIdx.x;
  if (i >= n4) return;
  float4 v = *(const float4*)&in[i * 4];
  ushort4 pk = {f2bf(v.x), f2bf(v.y), f2bf(v.z), f2bf(v.w)};
  *(ushort4*)&out[i * 4] = pk;
}

// ---------------- silu(c) + mods matvec ----------------------------------
__global__ void silu_kernel(const float* __restrict__ c, float* __restrict__ sc) {
  int i = blockIdx.x * 256 + threadIdx.x;
  float v = c[i];
  sc[i] = v / (1.f + __expf(-v));
}
__global__ void mods_kernel(const float* __restrict__ sc, const float* __restrict__ aw,
                            const float* __restrict__ ab, float* __restrict__ mods) {
  int j = blockIdx.x * 256 + threadIdx.x;
  int b = blockIdx.y;
  const float* s = sc + b * DD;
  float acc = ab[j];
  for (int d = 0; d < DD; ++d) acc = fmaf(s[d], aw[(long)d * MODS_LD + j], acc);
  mods[(long)b * MODS_LD + j] = acc;
}

// ---------------- fused RMSNorm + modulate -> bf16 ------------------------
__global__ __launch_bounds__(256) void rmsmod_kernel(const float* __restrict__ x,
                                                     const float* __restrict__ w,
                                                     const float* __restrict__ mods,
                                                     int shiftOff, int scaleOff,
                                                     u16* __restrict__ out) {
  long row = blockIdx.x;
  int b = (int)(row >> 10);
  int t = threadIdx.x;
  const float* xr = x + row * DD;
  float4 v = *(const float4*)&xr[t * 4];
  float ss = v.x * v.x + v.y * v.y + v.z * v.z + v.w * v.w;
#pragma unroll
  for (int msk = 1; msk < 64; msk <<= 1) ss += __shfl_xor(ss, msk);
  __shared__ float red[4];
  if ((t & 63) == 0) red[t >> 6] = ss;
  __syncthreads();
  float tot = red[0] + red[1] + red[2] + red[3];
  float inv = rsqrtf(tot * (1.f / DD) + 1e-6f);
  const float* mrow = mods + (long)b * MODS_LD;
  float vv[4] = {v.x, v.y, v.z, v.w};
  u16 tmp[4];
#pragma unroll
  for (int j = 0; j < 4; ++j) {
    int c = t * 4 + j;
    float rr = vv[j] * inv * w[c] * (1.f + mrow[scaleOff + c]) + mrow[shiftOff + c];
    tmp[j] = f2bf(rr);
  }
  ushort4 pk = {tmp[0], tmp[1], tmp[2], tmp[3]};
  *(ushort4*)&out[row * DD + t * 4] = pk;
}

// ---------------- GEMM: C = A(bf16, rows x K) @ Bt(bf16, cols x K)^T ------
// MODE 0: outb[idx] = bf16(acc + bias)
// MODE 1: outf[idx] = xin[idx] + mods[b*9216+gateOff+col] * (acc + bias)
template <int MODE>
__global__ __launch_bounds__(256, 2) void gemm_bf16(
    const u16* __restrict__ A, const u16* __restrict__ Bt, int K, int ldc,
    const float* __restrict__ bias, int biasN, u16* __restrict__ outb,
    float* __restrict__ outf, const float* __restrict__ xin,
    const float* __restrict__ mods, int gateOff) {
  __shared__ u16 As[128 * 64];
  __shared__ u16 Bs[128 * 64];
  int t = threadIdx.x;
  int l = t & 63, w = t >> 6;
  int wr = w >> 1, wc = w & 1;
  int lg = l >> 4, ll = l & 15;
  long rowTile = (long)blockIdx.y * 128;
  long colTile = (long)blockIdx.x * 128;
  const u16* Ap = A + rowTile * K;
  const u16* Bp = Bt + colTile * K;
  int srow = t >> 3;
  int scol = (t & 7) * 8;

  f32x4 acc[4][4] = {};

  for (int k0 = 0; k0 < K; k0 += 64) {
#pragma unroll
    for (int i = 0; i < 4; ++i)
      gload_lds16(Ap + (long)(i * 32 + srow) * K + k0 + scol, &As[(i * 256 + t) * 8]);
#pragma unroll
    for (int i = 0; i < 4; ++i)
      gload_lds16(Bp + (long)(i * 32 + srow) * K + k0 + scol, &Bs[(i * 256 + t) * 8]);
    __syncthreads();
#pragma unroll
    for (int kk = 0; kk < 2; ++kk) {
      short8 af[4], bfr[4];
#pragma unroll
      for (int m2 = 0; m2 < 4; ++m2)
        af[m2] = *(const short8*)&As[(wr * 64 + m2 * 16 + ll) * 64 + kk * 32 + lg * 8];
#pragma unroll
      for (int n2 = 0; n2 < 4; ++n2)
        bfr[n2] = *(const short8*)&Bs[(wc * 64 + n2 * 16 + ll) * 64 + kk * 32 + lg * 8];
#pragma unroll
      for (int m2 = 0; m2 < 4; ++m2)
#pragma unroll
        for (int n2 = 0; n2 < 4; ++n2)
          acc[m2][n2] =
              __builtin_amdgcn_mfma_f32_16x16x32_bf16(af[m2], bfr[n2], acc[m2][n2], 0, 0, 0);
    }
    __syncthreads();
  }
#pragma unroll
  for (int n2 = 0; n2 < 4; ++n2) {
    long cg = colTile + wc * 64 + n2 * 16 + ll;
    float bv = (cg < biasN) ? bias[cg] : 0.f;
#pragma unroll
    for (int m2 = 0; m2 < 4; ++m2) {
#pragma unroll
      for (int r = 0; r < 4; ++r) {
        long rg = rowTile + wr * 64 + m2 * 16 + lg * 4 + r;
        float v = acc[m2][n2][r] + bv;
        long idx = rg * ldc + cg;
        if (MODE == 0) {
          outb[idx] = f2bf(v);
        } else {
          int bb = (int)(rg >> 10);
          outf[idx] = xin[idx] + mods[(long)bb * MODS_LD + gateOff + cg] * v;
        }
      }
    }
  }
}

// ---------------- flash attention (64 q-rows/block, 4 waves) --------------
// q/k RMS-norm (weights qn/kn) applied at staging; softmax scale folded in Q.
__global__ __launch_bounds__(256, 2) void attn_kernel(
    const u16* __restrict__ qb, int qStride, const u16* __restrict__ kb,
    const u16* __restrict__ vb, int kvStride, const float* __restrict__ qn,
    const float* __restrict__ kn, u16* __restrict__ outp, int Nk, int Mpb) {
  __shared__ u16 Qs[64 * 64], Ks[64 * 64], Vt[64 * 64];
  __shared__ u16 Ps[4][16 * 64];
  int t = threadIdx.x, w = t >> 6, l = t & 63;
  int qt = blockIdx.x, h = blockIdx.y, b = blockIdx.z;
  int lg = l >> 4, ll = l & 15;

  {  // Q tile, rms-normed, * qn * HD^-0.5
    int row = t >> 2, p = t & 3;
    const u16* src = qb + ((long)(b * NN + qt * 64 + row)) * qStride + h * 64 + p * 16;
    short8 a0 = *(const short8*)src;
    short8 a1 = *(const short8*)(src + 8);
    float v[16];
    float ss = 0.f;
#pragma unroll
    for (int j = 0; j < 8; ++j) { v[j] = bf2f((u16)a0[j]); v[8 + j] = bf2f((u16)a1[j]); }
#pragma unroll
    for (int j = 0; j < 16; ++j) ss += v[j] * v[j];
    ss += __shfl_xor(ss, 1);
    ss += __shfl_xor(ss, 2);
    float inv = rsqrtf(ss * (1.f / 64) + 1e-6f) * 0.125f;
#pragma unroll
    for (int j = 0; j < 16; ++j) Qs[row * 64 + p * 16 + j] = f2bf(v[j] * inv * qn[p * 16 + j]);
  }
  __syncthreads();
  short8 qf0 = *(const short8*)&Qs[(w * 16 + ll) * 64 + lg * 8];
  short8 qf1 = *(const short8*)&Qs[(w * 16 + ll) * 64 + 32 + lg * 8];

  float m[4], ssum[4];
  f32x4 o[4] = {};
#pragma unroll
  for (int r = 0; r < 4; ++r) { m[r] = -1e30f; ssum[r] = 0.f; }

  for (int kt = 0; kt < Nk; kt += 64) {
    __syncthreads();
    {  // stage K (rms*kn) and V^T
      int row = t >> 2, p = t & 3;
      const u16* ksrc = kb + ((long)(b * Mpb + kt + row)) * kvStride + h * 64 + p * 16;
      short8 a0 = *(const short8*)ksrc;
      short8 a1 = *(const short8*)(ksrc + 8);
      float v[16];
      float ss = 0.f;
#pragma unroll
      for (int j = 0; j < 8; ++j) { v[j] = bf2f((u16)a0[j]); v[8 + j] = bf2f((u16)a1[j]); }
#pragma unroll
      for (int j = 0; j < 16; ++j) ss += v[j] * v[j];
      ss += __shfl_xor(ss, 1);
      ss += __shfl_xor(ss, 2);
      float inv = rsqrtf(ss * (1.f / 64) + 1e-6f);
#pragma unroll
      for (int j = 0; j < 16; ++j) Ks[row * 64 + p * 16 + j] = f2bf(v[j] * inv * kn[p * 16 + j]);
      const u16* vsrc = vb + ((long)(b * Mpb + kt + row)) * kvStride + h * 64 + p * 16;
      short8 b0 = *(const short8*)vsrc;
      short8 b1 = *(const short8*)(vsrc + 8);
#pragma unroll
      for (int j = 0; j < 8; ++j) {
        Vt[(p * 16 + j) * 64 + row] = (u16)b0[j];
        Vt[(p * 16 + 8 + j) * 64 + row] = (u16)b1[j];
      }
    }
    __syncthreads();
    // S = Q K^T  (16 q-rows x 64 keys per wave)
    f32x4 s[4] = {};
#pragma unroll
    for (int n = 0; n < 4; ++n) {
      short8 kf0 = *(const short8*)&Ks[(n * 16 + ll) * 64 + lg * 8];
      short8 kf1 = *(const short8*)&Ks[(n * 16 + ll) * 64 + 32 + lg * 8];
      s[n] = __builtin_amdgcn_mfma_f32_16x16x32_bf16(qf0, kf0, s[n], 0, 0, 0);
      s[n] = __builtin_amdgcn_mfma_f32_16x16x32_bf16(qf1, kf1, s[n], 0, 0, 0);
    }
    // online softmax (rows = lg*4+r, key lanes = ll)
    float p_[4][4];
#pragma unroll
    for (int r = 0; r < 4; ++r) {
      float pm = fmaxf(fmaxf(s[0][r], s[1][r]), fmaxf(s[2][r], s[3][r]));
      pm = fmaxf(pm, __shfl_xor(pm, 1));
      pm = fmaxf(pm, __shfl_xor(pm, 2));
      pm = fmaxf(pm, __shfl_xor(pm, 4));
      pm = fmaxf(pm, __shfl_xor(pm, 8));
      float nm = fmaxf(m[r], pm);
      float alpha = __expf(m[r] - nm);
      float rs = 0.f;
#pragma unroll
      for (int n = 0; n < 4; ++n) {
        float pv = __expf(s[n][r] - nm);
        p_[n][r] = pv;
        rs += pv;
      }
      rs += __shfl_xor(rs, 1);
      rs += __shfl_xor(rs, 2);
      rs += __shfl_xor(rs, 4);
      rs += __shfl_xor(rs, 8);
      ssum[r] = ssum[r] * alpha + rs;
      m[r] = nm;
#pragma unroll
      for (int n = 0; n < 4; ++n) o[n][r] *= alpha;
    }
    // P -> per-wave LDS, reload as MFMA A-operand
#pragma unroll
    for (int n = 0; n < 4; ++n)
#pragma unroll
      for (int r = 0; r < 4; ++r) Ps[w][(lg * 4 + r) * 64 + n * 16 + ll] = f2bf(p_[n][r]);
    short8 pf0 = *(const short8*)&Ps[w][ll * 64 + lg * 8];
    short8 pf1 = *(const short8*)&Ps[w][ll * 64 + 32 + lg * 8];
#pragma unroll
    for (int n = 0; n < 4; ++n) {
      short8 vf0 = *(const short8*)&Vt[(n * 16 + ll) * 64 + lg * 8];
      short8 vf1 = *(const short8*)&Vt[(n * 16 + ll) * 64 + 32 + lg * 8];
      o[n] = __builtin_amdgcn_mfma_f32_16x16x32_bf16(pf0, vf0, o[n], 0, 0, 0);
      o[n] = __builtin_amdgcn_mfma_f32_16x16x32_bf16(pf1, vf1, o[n], 0, 0, 0);
    }
  }
#pragma unroll
  for (int n = 0; n < 4; ++n)
#pragma unroll
    for (int r = 0; r < 4; ++r) {
      long row = (long)b * NN + qt * 64 + w * 16 + lg * 4 + r;
      int col = h * 64 + n * 16 + ll;
      outp[row * DD + col] = f2bf(o[n][r] / ssum[r]);
    }
}

// ---------------- SwiGLU combine: h1 = silu(h1)*h2 ------------------------
__global__ void swiglu_kernel(u16* __restrict__ h1, const u16* __restrict__ h2, long n4) {
  long i = (long)blockIdx.x * 256 + threadIdx.x;
  if (i >= n4) return;
  ushort4 a = *(ushort4*)&h1[i * 4];
  ushort4 bq = *(const ushort4*)&h2[i * 4];
  u16 va[4] = {a.x, a.y, a.z, a.w}, vb[4] = {bq.x, bq.y, bq.z, bq.w};
  u16 oo[4];
#pragma unroll
  for (int j = 0; j < 4; ++j) {
    float f = bf2f(va[j]);
    float g = f / (1.f + __expf(-f));
    oo[j] = f2bf(g * bf2f(vb[j]));
  }
  ushort4 pk = {oo[0], oo[1], oo[2], oo[3]};
  *(ushort4*)&h1[i * 4] = pk;
}

extern "C" void kernel_launch(void* const* d_in, const int* in_sizes, int n_in,
                              void* d_out, int out_size, void* d_ws, size_t ws_size,
                              hipStream_t stream) {
  const float* x = (const float*)d_in[0];
  const float* src = (const float*)d_in[1];
  const float* c = (const float*)d_in[2];
  const float* ada_w = (const float*)d_in[3];
  const float* ada_b = (const float*)d_in[4];
  const float* n1_w = (const float*)d_in[5];
  const float* nc_w = (const float*)d_in[6];
  const float* n2_w = (const float*)d_in[7];
  const float* sa_qkv_w = (const float*)d_in[8];
  const float* sa_qkv_b = (const float*)d_in[9];
  const float* sa_qn_w = (const float*)d_in[10];
  const float* sa_kn_w = (const float*)d_in[11];
  const float* sa_o_w = (const float*)d_in[12];
  const float* sa_o_b = (const float*)d_in[13];
  const float* ca_q_w = (const float*)d_in[14];
  const float* ca_q_b = (const float*)d_in[15];
  const float* ca_kv_w = (const float*)d_in[16];
  const float* ca_kv_b = (const float*)d_in[17];
  const float* ca_qn_w = (const float*)d_in[18];
  const float* ca_kn_w = (const float*)d_in[19];
  const float* ca_o_w = (const float*)d_in[20];
  const float* ca_o_b = (const float*)d_in[21];
  const float* mlp_w1 = (const float*)d_in[22];
  const float* mlp_b1 = (const float*)d_in[23];
  const float* mlp_w2 = (const float*)d_in[24];
  const float* mlp_b2 = (const float*)d_in[25];
  const float* mlp_w3 = (const float*)d_in[26];
  const float* mlp_b3 = (const float*)d_in[27];
  float* out = (float*)d_out;

  char* p = (char*)d_ws;
  auto alloc = [&](size_t bytes) {
    char* r = p;
    p += (bytes + 255) & ~(size_t)255;
    return r;
  };
  float* mods = (float*)alloc(4l * 9216 * 4);
  float* sc = (float*)alloc(4096l * 4);
  u16* qkvT = (u16*)alloc(3072l * 1024 * 2);
  u16* saoT = (u16*)alloc(1024l * 1024 * 2);
  u16* caqT = (u16*)alloc(1024l * 1024 * 2);
  u16* cakvT = (u16*)alloc(2048l * 1024 * 2);
  u16* caoT = (u16*)alloc(1024l * 1024 * 2);
  u16* w1T = (u16*)alloc(2816l * 1024 * 2);
  u16* w2T = (u16*)alloc(2816l * 1024 * 2);
  u16* w3T = (u16*)alloc(1024l * 2816 * 2);
  u16* xnb = (u16*)alloc(4096l * 1024 * 2);
  u16* srcb = (u16*)alloc(4096l * 1024 * 2);
  u16* bufA = (u16*)alloc(4096l * 3072 * 2);
  u16* bufB = (u16*)alloc(4096l * 2816 * 2);
  u16* attO = (u16*)alloc(4096l * 1024 * 2);

  dim3 tb(32, 8);
  transpose_convert<<<dim3(32, 96), tb, 0, stream>>>(sa_qkv_w, qkvT, 1024, 3072, 1024, 3072);
  transpose_convert<<<dim3(32, 32), tb, 0, stream>>>(sa_o_w, saoT, 1024, 1024, 1024, 1024);
  transpose_convert<<<dim3(32, 32), tb, 0, stream>>>(ca_q_w, caqT, 1024, 1024, 1024, 1024);
  transpose_convert<<<dim3(32, 64), tb, 0, stream>>>(ca_kv_w, cakvT, 1024, 2048, 1024, 2048);
  transpose_convert<<<dim3(32, 32), tb, 0, stream>>>(ca_o_w, caoT, 1024, 1024, 1024, 1024);
  transpose_convert<<<dim3(32, 88), tb, 0, stream>>>(mlp_w1, w1T, 1024, 2730, 1024, 2816);
  transpose_convert<<<dim3(32, 88), tb, 0, stream>>>(mlp_w2, w2T, 1024, 2730, 1024, 2816);
  transpose_convert<<<dim3(88, 32), tb, 0, stream>>>(mlp_w3, w3T, 2730, 1024, 2816, 1024);
  cvt_bf16_kernel<<<4096, 256, 0, stream>>>(src, srcb, 4096l * 1024 / 4);
  silu_kernel<<<16, 256, 0, stream>>>(c, sc);
  mods_kernel<<<dim3(36, 4), 256, 0, stream>>>(sc, ada_w, ada_b, mods);

  // ---- self-attention sublayer
  rmsmod_kernel<<<4096, 256, 0, stream>>>(x, n1_w, mods, 0, 1024, xnb);
  gemm_bf16<0><<<dim3(24, 32), 256, 0, stream>>>(xnb, qkvT, 1024, 3072, sa_qkv_b, 3072, bufA,
                                                 nullptr, nullptr, nullptr, 0);
  attn_kernel<<<dim3(16, 16, 4), 256, 0, stream>>>(bufA, 3072, bufA + 1024, bufA + 2048, 3072,
                                                   sa_qn_w, sa_kn_w, attO, 1024, 1024);
  gemm_bf16<1><<<dim3(8, 32), 256, 0, stream>>>(attO, saoT, 1024, 1024, sa_o_b, 1024, nullptr,
                                                out, x, mods, 2048);

  // ---- cross-attention sublayer
  rmsmod_kernel<<<4096, 256, 0, stream>>>(out, nc_w, mods, 3072, 4096, xnb);
  gemm_bf16<0><<<dim3(8, 32), 256, 0, stream>>>(xnb, caqT, 1024, 1024, ca_q_b, 1024, bufA,
                                                nullptr, nullptr, nullptr, 0);
  gemm_bf16<0><<<dim3(16, 32), 256, 0, stream>>>(srcb, cakvT, 1024, 2048, ca_kv_b, 2048, bufB,
                                                 nullptr, nullptr, nullptr, 0);
  attn_kernel<<<dim3(16, 16, 4), 256, 0, stream>>>(bufA, 1024, bufB, bufB + 1024, 2048, ca_qn_w,
                                                   ca_kn_w, attO, 1024, 1024);
  gemm_bf16<1><<<dim3(8, 32), 256, 0, stream>>>(attO, caoT, 1024, 1024, ca_o_b, 1024, nullptr,
                                                out, out, mods, 5120);

  // ---- SwiGLU FFN sublayer
  rmsmod_kernel<<<4096, 256, 0, stream>>>(out, n2_w, mods, 6144, 7168, xnb);
  gemm_bf16<0><<<dim3(22, 32), 256, 0, stream>>>(xnb, w1T, 1024, 2816, mlp_b1, 2730, bufA,
                                                 nullptr, nullptr, nullptr, 0);
  gemm_bf16<0><<<dim3(22, 32), 256, 0, stream>>>(xnb, w2T, 1024, 2816, mlp_b2, 2730, bufB,
                                                 nullptr, nullptr, nullptr, 0);
  swiglu_kernel<<<(int)((4096l * 2816 / 4 + 255) / 256), 256, 0, stream>>>(bufA, bufB,
                                                                           4096l * 2816 / 4);
  gemm_bf16<1><<<dim3(8, 32), 256, 0, stream>>>(bufA, w3T, 2816, 1024, mlp_b3, 1024, nullptr,
                                                out, out, mods, 8192);
}

// Round 2
// 570.884 us; speedup vs baseline: 1.1264x; 1.1264x over previous
//
#include <hip/hip_runtime.h>

typedef unsigned short u16;
typedef __attribute__((ext_vector_type(8))) short short8;
typedef __attribute__((ext_vector_type(4))) float f32x4;

#define DD 1024
#define NN 1024
#define MODS_LD 9216

__device__ __forceinline__ float bf2f(u16 v) {
  unsigned int u = ((unsigned int)v) << 16;
  return __builtin_bit_cast(float, u);
}
__device__ __forceinline__ u16 f2bf(float f) {
  unsigned int u = __builtin_bit_cast(unsigned int, f);
  unsigned int lsb = (u >> 16) & 1;
  u += 0x7fffu + lsb;
  return (u16)(u >> 16);
}

__device__ __forceinline__ void gload_lds16(const u16* g, u16* l) {
  __builtin_amdgcn_global_load_lds(
      (const __attribute__((address_space(1))) unsigned int*)g,
      (__attribute__((address_space(3))) unsigned int*)l, 16, 0, 0);
}

// ---------------- weight transpose + fp32->bf16 -------------------------
// src: R x C fp32 row-major. dst: C2 x R2 bf16 row-major, dst[c][r]=src[r][c], 0-padded.
__global__ void transpose_convert(const float* __restrict__ src, u16* __restrict__ dst,
                                  int R, int C, int R2, int C2) {
  __shared__ float tile[32][33];
  int tx = threadIdx.x, ty = threadIdx.y;
  int r0 = blockIdx.x * 32, c0 = blockIdx.y * 32;
#pragma unroll
  for (int i = 0; i < 4; ++i) {
    int r = r0 + ty + i * 8, c = c0 + tx;
    tile[ty + i * 8][tx] = (r < R && c < C) ? src[(long)r * C + c] : 0.f;
  }
  __syncthreads();
#pragma unroll
  for (int i = 0; i < 4; ++i) {
    int c = c0 + ty + i * 8, r = r0 + tx;
    if (c < C2 && r < R2) dst[(long)c * R2 + r] = f2bf(tile[tx][ty + i * 8]);
  }
}

// ---------------- fp32 -> bf16 (vector) ---------------------------------
__global__ void cvt_bf16_kernel(const float* __restrict__ in, u16* __restrict__ out, long n4) {
  long i = (long)blockIdx.x * 256 + threadIdx.x;
  if (i >= n4) return;
  float4 v = *(const float4*)&in[i * 4];
  ushort4 pk = {f2bf(v.x), f2bf(v.y), f2bf(v.z), f2bf(v.w)};
  *(ushort4*)&out[i * 4] = pk;
}

// ---------------- silu(c) + mods matvec (k-split, deterministic) ----------
__global__ void silu_kernel(const float* __restrict__ c, float* __restrict__ sc) {
  int i = blockIdx.x * 256 + threadIdx.x;
  float v = c[i];
  sc[i] = v / (1.f + __expf(-v));
}

#define MODS_KS 32
// grid (36, 32): j = bx*256+tx, d-slice = by*32.  part[(ks*4+b)*9216 + j]
__global__ __launch_bounds__(256) void mods_partial(const float* __restrict__ sc,
                                                    const float* __restrict__ aw,
                                                    float* __restrict__ part) {
  int j = blockIdx.x * 256 + threadIdx.x;
  int ks = blockIdx.y;
  int d0 = ks * (DD / MODS_KS);
  float a0 = 0.f, a1 = 0.f, a2 = 0.f, a3 = 0.f;
#pragma unroll 8
  for (int d = d0; d < d0 + DD / MODS_KS; ++d) {
    float w = aw[(long)d * MODS_LD + j];
    a0 = fmaf(sc[d], w, a0);
    a1 = fmaf(sc[DD + d], w, a1);
    a2 = fmaf(sc[2 * DD + d], w, a2);
    a3 = fmaf(sc[3 * DD + d], w, a3);
  }
  long base = (long)ks * 4 * MODS_LD + j;
  part[base] = a0;
  part[base + MODS_LD] = a1;
  part[base + 2 * MODS_LD] = a2;
  part[base + 3 * MODS_LD] = a3;
}

// grid (36, 4): mods[b*9216+j] = ab[j] + sum_ks part[(ks*4+b)*9216+j]
__global__ __launch_bounds__(256) void mods_reduce(const float* __restrict__ part,
                                                   const float* __restrict__ ab,
                                                   float* __restrict__ mods) {
  int j = blockIdx.x * 256 + threadIdx.x;
  int b = blockIdx.y;
  float acc = ab[j];
#pragma unroll
  for (int ks = 0; ks < MODS_KS; ++ks) acc += part[((long)ks * 4 + b) * MODS_LD + j];
  mods[(long)b * MODS_LD + j] = acc;
}

// ---------------- fused RMSNorm + modulate -> bf16 ------------------------
__global__ __launch_bounds__(256) void rmsmod_kernel(const float* __restrict__ x,
                                                     const float* __restrict__ w,
                                                     const float* __restrict__ mods,
                                                     int shiftOff, int scaleOff,
                                                     u16* __restrict__ out) {
  long row = blockIdx.x;
  int b = (int)(row >> 10);
  int t = threadIdx.x;
  const float* xr = x + row * DD;
  float4 v = *(const float4*)&xr[t * 4];
  float ss = v.x * v.x + v.y * v.y + v.z * v.z + v.w * v.w;
#pragma unroll
  for (int msk = 1; msk < 64; msk <<= 1) ss += __shfl_xor(ss, msk);
  __shared__ float red[4];
  if ((t & 63) == 0) red[t >> 6] = ss;
  __syncthreads();
  float tot = red[0] + red[1] + red[2] + red[3];
  float inv = rsqrtf(tot * (1.f / DD) + 1e-6f);
  const float* mrow = mods + (long)b * MODS_LD;
  float vv[4] = {v.x, v.y, v.z, v.w};
  u16 tmp[4];
#pragma unroll
  for (int j = 0; j < 4; ++j) {
    int c = t * 4 + j;
    float rr = vv[j] * inv * w[c] * (1.f + mrow[scaleOff + c]) + mrow[shiftOff + c];
    tmp[j] = f2bf(rr);
  }
  ushort4 pk = {tmp[0], tmp[1], tmp[2], tmp[3]};
  *(ushort4*)&out[row * DD + t * 4] = pk;
}

// ---------------- GEMM: C = A(bf16, rows x K) @ Bt(bf16, cols x K)^T ------
// MODE 0: outb[idx] = bf16(acc + bias)
// MODE 1: outf[idx] = xin[idx] + mods[b*9216+gateOff+col] * (acc + bias)
template <int MODE>
__global__ __launch_bounds__(256, 2) void gemm_bf16(
    const u16* __restrict__ A, const u16* __restrict__ Bt, int K, int ldc,
    const float* __restrict__ bias, int biasN, u16* __restrict__ outb,
    float* __restrict__ outf, const float* __restrict__ xin,
    const float* __restrict__ mods, int gateOff) {
  __shared__ u16 As[128 * 64];
  __shared__ u16 Bs[128 * 64];
  int t = threadIdx.x;
  int l = t & 63, w = t >> 6;
  int wr = w >> 1, wc = w & 1;
  int lg = l >> 4, ll = l & 15;
  long rowTile = (long)blockIdx.y * 128;
  long colTile = (long)blockIdx.x * 128;
  const u16* Ap = A + rowTile * K;
  const u16* Bp = Bt + colTile * K;
  int srow = t >> 3;
  int scol = (t & 7) * 8;

  f32x4 acc[4][4] = {};

  for (int k0 = 0; k0 < K; k0 += 64) {
#pragma unroll
    for (int i = 0; i < 4; ++i)
      gload_lds16(Ap + (long)(i * 32 + srow) * K + k0 + scol, &As[(i * 256 + t) * 8]);
#pragma unroll
    for (int i = 0; i < 4; ++i)
      gload_lds16(Bp + (long)(i * 32 + srow) * K + k0 + scol, &Bs[(i * 256 + t) * 8]);
    __syncthreads();
#pragma unroll
    for (int kk = 0; kk < 2; ++kk) {
      short8 af[4], bfr[4];
#pragma unroll
      for (int m2 = 0; m2 < 4; ++m2)
        af[m2] = *(const short8*)&As[(wr * 64 + m2 * 16 + ll) * 64 + kk * 32 + lg * 8];
#pragma unroll
      for (int n2 = 0; n2 < 4; ++n2)
        bfr[n2] = *(const short8*)&Bs[(wc * 64 + n2 * 16 + ll) * 64 + kk * 32 + lg * 8];
#pragma unroll
      for (int m2 = 0; m2 < 4; ++m2)
#pragma unroll
        for (int n2 = 0; n2 < 4; ++n2)
          acc[m2][n2] =
              __builtin_amdgcn_mfma_f32_16x16x32_bf16(af[m2], bfr[n2], acc[m2][n2], 0, 0, 0);
    }
    __syncthreads();
  }
#pragma unroll
  for (int n2 = 0; n2 < 4; ++n2) {
    long cg = colTile + wc * 64 + n2 * 16 + ll;
    float bv = (cg < biasN) ? bias[cg] : 0.f;
#pragma unroll
    for (int m2 = 0; m2 < 4; ++m2) {
#pragma unroll
      for (int r = 0; r < 4; ++r) {
        long rg = rowTile + wr * 64 + m2 * 16 + lg * 4 + r;
        float v = acc[m2][n2][r] + bv;
        long idx = rg * ldc + cg;
        if (MODE == 0) {
          outb[idx] = f2bf(v);
        } else {
          int bb = (int)(rg >> 10);
          outf[idx] = xin[idx] + mods[(long)bb * MODS_LD + gateOff + cg] * v;
        }
      }
    }
  }
}

// ---------------- flash attention (64 q-rows/block, 4 waves) --------------
__global__ __launch_bounds__(256, 2) void attn_kernel(
    const u16* __restrict__ qb, int qStride, const u16* __restrict__ kb,
    const u16* __restrict__ vb, int kvStride, const float* __restrict__ qn,
    const float* __restrict__ kn, u16* __restrict__ outp, int Nk, int Mpb) {
  __shared__ u16 Qs[64 * 64], Ks[64 * 64], Vt[64 * 64];
  __shared__ u16 Ps[4][16 * 64];
  int t = threadIdx.x, w = t >> 6, l = t & 63;
  int qt = blockIdx.x, h = blockIdx.y, b = blockIdx.z;
  int lg = l >> 4, ll = l & 15;

  {  // Q tile, rms-normed, * qn * HD^-0.5
    int row = t >> 2, p = t & 3;
    const u16* src = qb + ((long)(b * NN + qt * 64 + row)) * qStride + h * 64 + p * 16;
    short8 a0 = *(const short8*)src;
    short8 a1 = *(const short8*)(src + 8);
    float v[16];
    float ss = 0.f;
#pragma unroll
    for (int j = 0; j < 8; ++j) { v[j] = bf2f((u16)a0[j]); v[8 + j] = bf2f((u16)a1[j]); }
#pragma unroll
    for (int j = 0; j < 16; ++j) ss += v[j] * v[j];
    ss += __shfl_xor(ss, 1);
    ss += __shfl_xor(ss, 2);
    float inv = rsqrtf(ss * (1.f / 64) + 1e-6f) * 0.125f;
#pragma unroll
    for (int j = 0; j < 16; ++j) Qs[row * 64 + p * 16 + j] = f2bf(v[j] * inv * qn[p * 16 + j]);
  }
  __syncthreads();
  short8 qf0 = *(const short8*)&Qs[(w * 16 + ll) * 64 + lg * 8];
  short8 qf1 = *(const short8*)&Qs[(w * 16 + ll) * 64 + 32 + lg * 8];

  float m[4], ssum[4];
  f32x4 o[4] = {};
#pragma unroll
  for (int r = 0; r < 4; ++r) { m[r] = -1e30f; ssum[r] = 0.f; }

  for (int kt = 0; kt < Nk; kt += 64) {
    __syncthreads();
    {  // stage K (rms*kn) and V^T
      int row = t >> 2, p = t & 3;
      const u16* ksrc = kb + ((long)(b * Mpb + kt + row)) * kvStride + h * 64 + p * 16;
      short8 a0 = *(const short8*)ksrc;
      short8 a1 = *(const short8*)(ksrc + 8);
      float v[16];
      float ss = 0.f;
#pragma unroll
      for (int j = 0; j < 8; ++j) { v[j] = bf2f((u16)a0[j]); v[8 + j] = bf2f((u16)a1[j]); }
#pragma unroll
      for (int j = 0; j < 16; ++j) ss += v[j] * v[j];
      ss += __shfl_xor(ss, 1);
      ss += __shfl_xor(ss, 2);
      float inv = rsqrtf(ss * (1.f / 64) + 1e-6f);
#pragma unroll
      for (int j = 0; j < 16; ++j) Ks[row * 64 + p * 16 + j] = f2bf(v[j] * inv * kn[p * 16 + j]);
      const u16* vsrc = vb + ((long)(b * Mpb + kt + row)) * kvStride + h * 64 + p * 16;
      short8 b0 = *(const short8*)vsrc;
      short8 b1 = *(const short8*)(vsrc + 8);
#pragma unroll
      for (int j = 0; j < 8; ++j) {
        Vt[(p * 16 + j) * 64 + row] = (u16)b0[j];
        Vt[(p * 16 + 8 + j) * 64 + row] = (u16)b1[j];
      }
    }
    __syncthreads();
    // S = Q K^T  (16 q-rows x 64 keys per wave)
    f32x4 s[4] = {};
#pragma unroll
    for (int n = 0; n < 4; ++n) {
      short8 kf0 = *(const short8*)&Ks[(n * 16 + ll) * 64 + lg * 8];
      short8 kf1 = *(const short8*)&Ks[(n * 16 + ll) * 64 + 32 + lg * 8];
      s[n] = __builtin_amdgcn_mfma_f32_16x16x32_bf16(qf0, kf0, s[n], 0, 0, 0);
      s[n] = __builtin_amdgcn_mfma_f32_16x16x32_bf16(qf1, kf1, s[n], 0, 0, 0);
    }
    // online softmax (rows = lg*4+r, key lanes = ll)
    float p_[4][4];
#pragma unroll
    for (int r = 0; r < 4; ++r) {
      float pm = fmaxf(fmaxf(s[0][r], s[1][r]), fmaxf(s[2][r], s[3][r]));
      pm = fmaxf(pm, __shfl_xor(pm, 1));
      pm = fmaxf(pm, __shfl_xor(pm, 2));
      pm = fmaxf(pm, __shfl_xor(pm, 4));
      pm = fmaxf(pm, __shfl_xor(pm, 8));
      float nm = fmaxf(m[r], pm);
      float alpha = __expf(m[r] - nm);
      float rs = 0.f;
#pragma unroll
      for (int n = 0; n < 4; ++n) {
        float pv = __expf(s[n][r] - nm);
        p_[n][r] = pv;
        rs += pv;
      }
      rs += __shfl_xor(rs, 1);
      rs += __shfl_xor(rs, 2);
      rs += __shfl_xor(rs, 4);
      rs += __shfl_xor(rs, 8);
      ssum[r] = ssum[r] * alpha + rs;
      m[r] = nm;
#pragma unroll
      for (int n = 0; n < 4; ++n) o[n][r] *= alpha;
    }
    // P -> per-wave LDS, reload as MFMA A-operand
#pragma unroll
    for (int n = 0; n < 4; ++n)
#pragma unroll
      for (int r = 0; r < 4; ++r) Ps[w][(lg * 4 + r) * 64 + n * 16 + ll] = f2bf(p_[n][r]);
    short8 pf0 = *(const short8*)&Ps[w][ll * 64 + lg * 8];
    short8 pf1 = *(const short8*)&Ps[w][ll * 64 + 32 + lg * 8];
#pragma unroll
    for (int n = 0; n < 4; ++n) {
      short8 vf0 = *(const short8*)&Vt[(n * 16 + ll) * 64 + lg * 8];
      short8 vf1 = *(const short8*)&Vt[(n * 16 + ll) * 64 + 32 + lg * 8];
      o[n] = __builtin_amdgcn_mfma_f32_16x16x32_bf16(pf0, vf0, o[n], 0, 0, 0);
      o[n] = __builtin_amdgcn_mfma_f32_16x16x32_bf16(pf1, vf1, o[n], 0, 0, 0);
    }
  }
#pragma unroll
  for (int n = 0; n < 4; ++n)
#pragma unroll
    for (int r = 0; r < 4; ++r) {
      long row = (long)b * NN + qt * 64 + w * 16 + lg * 4 + r;
      int col = h * 64 + n * 16 + ll;
      outp[row * DD + col] = f2bf(o[n][r] / ssum[r]);
    }
}

// ---------------- SwiGLU combine: h1 = silu(h1)*h2 ------------------------
__global__ void swiglu_kernel(u16* __restrict__ h1, const u16* __restrict__ h2, long n4) {
  long i = (long)blockIdx.x * 256 + threadIdx.x;
  if (i >= n4) return;
  ushort4 a = *(ushort4*)&h1[i * 4];
  ushort4 bq = *(const ushort4*)&h2[i * 4];
  u16 va[4] = {a.x, a.y, a.z, a.w}, vb[4] = {bq.x, bq.y, bq.z, bq.w};
  u16 oo[4];
#pragma unroll
  for (int j = 0; j < 4; ++j) {
    float f = bf2f(va[j]);
    float g = f / (1.f + __expf(-f));
    oo[j] = f2bf(g * bf2f(vb[j]));
  }
  ushort4 pk = {oo[0], oo[1], oo[2], oo[3]};
  *(ushort4*)&h1[i * 4] = pk;
}

extern "C" void kernel_launch(void* const* d_in, const int* in_sizes, int n_in,
                              void* d_out, int out_size, void* d_ws, size_t ws_size,
                              hipStream_t stream) {
  const float* x = (const float*)d_in[0];
  const float* src = (const float*)d_in[1];
  const float* c = (const float*)d_in[2];
  const float* ada_w = (const float*)d_in[3];
  const float* ada_b = (const float*)d_in[4];
  const float* n1_w = (const float*)d_in[5];
  const float* nc_w = (const float*)d_in[6];
  const float* n2_w = (const float*)d_in[7];
  const float* sa_qkv_w = (const float*)d_in[8];
  const float* sa_qkv_b = (const float*)d_in[9];
  const float* sa_qn_w = (const float*)d_in[10];
  const float* sa_kn_w = (const float*)d_in[11];
  const float* sa_o_w = (const float*)d_in[12];
  const float* sa_o_b = (const float*)d_in[13];
  const float* ca_q_w = (const float*)d_in[14];
  const float* ca_q_b = (const float*)d_in[15];
  const float* ca_kv_w = (const float*)d_in[16];
  const float* ca_kv_b = (const float*)d_in[17];
  const float* ca_qn_w = (const float*)d_in[18];
  const float* ca_kn_w = (const float*)d_in[19];
  const float* ca_o_w = (const float*)d_in[20];
  const float* ca_o_b = (const float*)d_in[21];
  const float* mlp_w1 = (const float*)d_in[22];
  const float* mlp_b1 = (const float*)d_in[23];
  const float* mlp_w2 = (const float*)d_in[24];
  const float* mlp_b2 = (const float*)d_in[25];
  const float* mlp_w3 = (const float*)d_in[26];
  const float* mlp_b3 = (const float*)d_in[27];
  float* out = (float*)d_out;

  char* p = (char*)d_ws;
  auto alloc = [&](size_t bytes) {
    char* r = p;
    p += (bytes + 255) & ~(size_t)255;
    return r;
  };
  float* mods = (float*)alloc(4l * 9216 * 4);
  float* sc = (float*)alloc(4096l * 4);
  float* part = (float*)alloc((long)MODS_KS * 4 * 9216 * 4);
  u16* qkvT = (u16*)alloc(3072l * 1024 * 2);
  u16* saoT = (u16*)alloc(1024l * 1024 * 2);
  u16* caqT = (u16*)alloc(1024l * 1024 * 2);
  u16* cakvT = (u16*)alloc(2048l * 1024 * 2);
  u16* caoT = (u16*)alloc(1024l * 1024 * 2);
  u16* w1T = (u16*)alloc(2816l * 1024 * 2);
  u16* w2T = (u16*)alloc(2816l * 1024 * 2);
  u16* w3T = (u16*)alloc(1024l * 2816 * 2);
  u16* xnb = (u16*)alloc(4096l * 1024 * 2);
  u16* srcb = (u16*)alloc(4096l * 1024 * 2);
  u16* bufA = (u16*)alloc(4096l * 3072 * 2);
  u16* bufB = (u16*)alloc(4096l * 2816 * 2);
  u16* attO = (u16*)alloc(4096l * 1024 * 2);

  dim3 tb(32, 8);
  transpose_convert<<<dim3(32, 96), tb, 0, stream>>>(sa_qkv_w, qkvT, 1024, 3072, 1024, 3072);
  transpose_convert<<<dim3(32, 32), tb, 0, stream>>>(sa_o_w, saoT, 1024, 1024, 1024, 1024);
  transpose_convert<<<dim3(32, 32), tb, 0, stream>>>(ca_q_w, caqT, 1024, 1024, 1024, 1024);
  transpose_convert<<<dim3(32, 64), tb, 0, stream>>>(ca_kv_w, cakvT, 1024, 2048, 1024, 2048);
  transpose_convert<<<dim3(32, 32), tb, 0, stream>>>(ca_o_w, caoT, 1024, 1024, 1024, 1024);
  transpose_convert<<<dim3(32, 88), tb, 0, stream>>>(mlp_w1, w1T, 1024, 2730, 1024, 2816);
  transpose_convert<<<dim3(32, 88), tb, 0, stream>>>(mlp_w2, w2T, 1024, 2730, 1024, 2816);
  transpose_convert<<<dim3(88, 32), tb, 0, stream>>>(mlp_w3, w3T, 2730, 1024, 2816, 1024);
  cvt_bf16_kernel<<<4096, 256, 0, stream>>>(src, srcb, 4096l * 1024 / 4);
  silu_kernel<<<16, 256, 0, stream>>>(c, sc);
  mods_partial<<<dim3(36, MODS_KS), 256, 0, stream>>>(sc, ada_w, part);
  mods_reduce<<<dim3(36, 4), 256, 0, stream>>>(part, ada_b, mods);

  // ---- self-attention sublayer
  rmsmod_kernel<<<4096, 256, 0, stream>>>(x, n1_w, mods, 0, 1024, xnb);
  gemm_bf16<0><<<dim3(24, 32), 256, 0, stream>>>(xnb, qkvT, 1024, 3072, sa_qkv_b, 3072, bufA,
                                                 nullptr, nullptr, nullptr, 0);
  attn_kernel<<<dim3(16, 16, 4), 256, 0, stream>>>(bufA, 3072, bufA + 1024, bufA + 2048, 3072,
                                                   sa_qn_w, sa_kn_w, attO, 1024, 1024);
  gemm_bf16<1><<<dim3(8, 32), 256, 0, stream>>>(attO, saoT, 1024, 1024, sa_o_b, 1024, nullptr,
                                                out, x, mods, 2048);

  // ---- cross-attention sublayer
  rmsmod_kernel<<<4096, 256, 0, stream>>>(out, nc_w, mods, 3072, 4096, xnb);
  gemm_bf16<0><<<dim3(8, 32), 256, 0, stream>>>(xnb, caqT, 1024, 1024, ca_q_b, 1024, bufA,
                                                nullptr, nullptr, nullptr, 0);
  gemm_bf16<0><<<dim3(16, 32), 256, 0, stream>>>(srcb, cakvT, 1024, 2048, ca_kv_b, 2048, bufB,
                                                 nullptr, nullptr, nullptr, 0);
  attn_kernel<<<dim3(16, 16, 4), 256, 0, stream>>>(bufA, 1024, bufB, bufB + 1024, 2048, ca_qn_w,
                                                   ca_kn_w, attO, 1024, 1024);
  gemm_bf16<1><<<dim3(8, 32), 256, 0, stream>>>(attO, caoT, 1024, 1024, ca_o_b, 1024, nullptr,
                                                out, out, mods, 5120);

  // ---- SwiGLU FFN sublayer
  rmsmod_kernel<<<4096, 256, 0, stream>>>(out, n2_w, mods, 6144, 7168, xnb);
  gemm_bf16<0><<<dim3(22, 32), 256, 0, stream>>>(xnb, w1T, 1024, 2816, mlp_b1, 2730, bufA,
                                                 nullptr, nullptr, nullptr, 0);
  gemm_bf16<0><<<dim3(22, 32), 256, 0, stream>>>(xnb, w2T, 1024, 2816, mlp_b2, 2730, bufB,
                                                 nullptr, nullptr, nullptr, 0);
  swiglu_kernel<<<(int)((4096l * 2816 / 4 + 255) / 256), 256, 0, stream>>>(bufA, bufB,
                                                                           4096l * 2816 / 4);
  gemm_bf16<1><<<dim3(8, 32), 256, 0, stream>>>(bufA, w3T, 2816, 1024, mlp_b3, 1024, nullptr,
                                                out, out, mods, 8192);
}

// Round 3
// 522.189 us; speedup vs baseline: 1.2315x; 1.0932x over previous
//
#include <hip/hip_runtime.h>

typedef unsigned short u16;
typedef __attribute__((ext_vector_type(8))) short short8;
typedef __attribute__((ext_vector_type(4))) float f32x4;

#define DD 1024
#define NN 1024
#define MODS_LD 9216

__device__ __forceinline__ float bf2f(u16 v) {
  unsigned int u = ((unsigned int)v) << 16;
  return __builtin_bit_cast(float, u);
}
__device__ __forceinline__ u16 f2bf(float f) {
  unsigned int u = __builtin_bit_cast(unsigned int, f);
  unsigned int lsb = (u >> 16) & 1;
  u += 0x7fffu + lsb;
  return (u16)(u >> 16);
}

__device__ __forceinline__ void gload_lds16(const u16* g, u16* l) {
  __builtin_amdgcn_global_load_lds(
      (const __attribute__((address_space(1))) unsigned int*)g,
      (__attribute__((address_space(3))) unsigned int*)l, 16, 0, 0);
}

// ---------------- weight transpose + fp32->bf16 -------------------------
__global__ void transpose_convert(const float* __restrict__ src, u16* __restrict__ dst,
                                  int R, int C, int R2, int C2) {
  __shared__ float tile[32][33];
  int tx = threadIdx.x, ty = threadIdx.y;
  int r0 = blockIdx.x * 32, c0 = blockIdx.y * 32;
#pragma unroll
  for (int i = 0; i < 4; ++i) {
    int r = r0 + ty + i * 8, c = c0 + tx;
    tile[ty + i * 8][tx] = (r < R && c < C) ? src[(long)r * C + c] : 0.f;
  }
  __syncthreads();
#pragma unroll
  for (int i = 0; i < 4; ++i) {
    int c = c0 + ty + i * 8, r = r0 + tx;
    if (c < C2 && r < R2) dst[(long)c * R2 + r] = f2bf(tile[tx][ty + i * 8]);
  }
}

// ---------------- fp32 -> bf16 (vector) ---------------------------------
__global__ void cvt_bf16_kernel(const float* __restrict__ in, u16* __restrict__ out, long n4) {
  long i = (long)blockIdx.x * 256 + threadIdx.x;
  if (i >= n4) return;
  float4 v = *(const float4*)&in[i * 4];
  ushort4 pk = {f2bf(v.x), f2bf(v.y), f2bf(v.z), f2bf(v.w)};
  *(ushort4*)&out[i * 4] = pk;
}

// ---------------- silu(c) + mods matvec (k-split, deterministic) ----------
__global__ void silu_kernel(const float* __restrict__ c, float* __restrict__ sc) {
  int i = blockIdx.x * 256 + threadIdx.x;
  float v = c[i];
  sc[i] = v / (1.f + __expf(-v));
}

#define MODS_KS 32
__global__ __launch_bounds__(256) void mods_partial(const float* __restrict__ sc,
                                                    const float* __restrict__ aw,
                                                    float* __restrict__ part) {
  int j = blockIdx.x * 256 + threadIdx.x;
  int ks = blockIdx.y;
  int d0 = ks * (DD / MODS_KS);
  float a0 = 0.f, a1 = 0.f, a2 = 0.f, a3 = 0.f;
#pragma unroll 8
  for (int d = d0; d < d0 + DD / MODS_KS; ++d) {
    float w = aw[(long)d * MODS_LD + j];
    a0 = fmaf(sc[d], w, a0);
    a1 = fmaf(sc[DD + d], w, a1);
    a2 = fmaf(sc[2 * DD + d], w, a2);
    a3 = fmaf(sc[3 * DD + d], w, a3);
  }
  long base = (long)ks * 4 * MODS_LD + j;
  part[base] = a0;
  part[base + MODS_LD] = a1;
  part[base + 2 * MODS_LD] = a2;
  part[base + 3 * MODS_LD] = a3;
}

__global__ __launch_bounds__(256) void mods_reduce(const float* __restrict__ part,
                                                   const float* __restrict__ ab,
                                                   float* __restrict__ mods) {
  int j = blockIdx.x * 256 + threadIdx.x;
  int b = blockIdx.y;
  float acc = ab[j];
#pragma unroll
  for (int ks = 0; ks < MODS_KS; ++ks) acc += part[((long)ks * 4 + b) * MODS_LD + j];
  mods[(long)b * MODS_LD + j] = acc;
}

// ---------------- fused RMSNorm + modulate -> bf16 ------------------------
__global__ __launch_bounds__(256) void rmsmod_kernel(const float* __restrict__ x,
                                                     const float* __restrict__ w,
                                                     const float* __restrict__ mods,
                                                     int shiftOff, int scaleOff,
                                                     u16* __restrict__ out) {
  long row = blockIdx.x;
  int b = (int)(row >> 10);
  int t = threadIdx.x;
  const float* xr = x + row * DD;
  float4 v = *(const float4*)&xr[t * 4];
  float ss = v.x * v.x + v.y * v.y + v.z * v.z + v.w * v.w;
#pragma unroll
  for (int msk = 1; msk < 64; msk <<= 1) ss += __shfl_xor(ss, msk);
  __shared__ float red[4];
  if ((t & 63) == 0) red[t >> 6] = ss;
  __syncthreads();
  float tot = red[0] + red[1] + red[2] + red[3];
  float inv = rsqrtf(tot * (1.f / DD) + 1e-6f);
  const float* mrow = mods + (long)b * MODS_LD;
  float vv[4] = {v.x, v.y, v.z, v.w};
  u16 tmp[4];
#pragma unroll
  for (int j = 0; j < 4; ++j) {
    int c = t * 4 + j;
    float rr = vv[j] * inv * w[c] * (1.f + mrow[scaleOff + c]) + mrow[shiftOff + c];
    tmp[j] = f2bf(rr);
  }
  ushort4 pk = {tmp[0], tmp[1], tmp[2], tmp[3]};
  *(ushort4*)&out[row * DD + t * 4] = pk;
}

// ---------------- q/k head-RMS-norm, in-place, vectorized -----------------
// One block per token row; 16 groups of 16 lanes, one head each (HD=64).
__global__ __launch_bounds__(256) void qknorm_kernel(u16* __restrict__ buf, int ld,
                                                     const float* __restrict__ w, float scale) {
  long row = blockIdx.x;
  int t = threadIdx.x;
  int g = t >> 4, p = t & 15;
  u16* ptr = buf + row * ld + g * 64 + p * 4;
  ushort4 a = *(ushort4*)ptr;
  float v[4] = {bf2f(a.x), bf2f(a.y), bf2f(a.z), bf2f(a.w)};
  float ss = v[0] * v[0] + v[1] * v[1] + v[2] * v[2] + v[3] * v[3];
  ss += __shfl_xor(ss, 1);
  ss += __shfl_xor(ss, 2);
  ss += __shfl_xor(ss, 4);
  ss += __shfl_xor(ss, 8);
  float inv = rsqrtf(ss * (1.f / 64) + 1e-6f) * scale;
  u16 o[4];
#pragma unroll
  for (int j = 0; j < 4; ++j) o[j] = f2bf(v[j] * inv * w[p * 4 + j]);
  ushort4 pk = {o[0], o[1], o[2], o[3]};
  *(ushort4*)ptr = pk;
}

// ---------------- V pre-transpose: v[b, kv, (h,d)] -> vt[(b,h), d, kv] -----
__global__ void vtrans_kernel(const u16* __restrict__ vb, int kvStride, int Mpb,
                              u16* __restrict__ vt) {
  __shared__ u16 tile[64][66];
  int t = threadIdx.x;
  int kt = blockIdx.x, h = blockIdx.y, b = blockIdx.z;
  const u16* base = vb + ((long)(b * Mpb + kt * 64)) * kvStride + h * 64;
#pragma unroll
  for (int sh = 0; sh < 2; ++sh) {
    int r = sh * 32 + (t >> 3);
    int c0 = (t & 7) * 8;
    short8 vv = *(const short8*)(base + (long)r * kvStride + c0);
#pragma unroll
    for (int j = 0; j < 8; ++j) tile[c0 + j][r] = (u16)vv[j];
  }
  __syncthreads();
  u16* obase = vt + ((long)(b * 16 + h) * 64) * 1024 + kt * 64;
#pragma unroll
  for (int sh = 0; sh < 2; ++sh) {
    int d = sh * 32 + (t >> 3);
    int c0 = (t & 7) * 8;
    u16 tmp[8];
#pragma unroll
    for (int j = 0; j < 8; ++j) tmp[j] = tile[d][c0 + j];
    *(short8*)(obase + (long)d * 1024 + c0) = *(short8*)tmp;
  }
}

// ---------------- GEMM: C = A(bf16, rows x K) @ Bt(bf16, cols x K)^T ------
template <int MODE>
__global__ __launch_bounds__(256, 2) void gemm_bf16(
    const u16* __restrict__ A, const u16* __restrict__ Bt, int K, int ldc,
    const float* __restrict__ bias, int biasN, u16* __restrict__ outb,
    float* __restrict__ outf, const float* __restrict__ xin,
    const float* __restrict__ mods, int gateOff) {
  __shared__ u16 As[128 * 64];
  __shared__ u16 Bs[128 * 64];
  int t = threadIdx.x;
  int l = t & 63, w = t >> 6;
  int wr = w >> 1, wc = w & 1;
  int lg = l >> 4, ll = l & 15;
  long rowTile = (long)blockIdx.y * 128;
  long colTile = (long)blockIdx.x * 128;
  const u16* Ap = A + rowTile * K;
  const u16* Bp = Bt + colTile * K;
  int srow = t >> 3;
  int scol = (t & 7) * 8;

  f32x4 acc[4][4] = {};

  for (int k0 = 0; k0 < K; k0 += 64) {
#pragma unroll
    for (int i = 0; i < 4; ++i)
      gload_lds16(Ap + (long)(i * 32 + srow) * K + k0 + scol, &As[(i * 256 + t) * 8]);
#pragma unroll
    for (int i = 0; i < 4; ++i)
      gload_lds16(Bp + (long)(i * 32 + srow) * K + k0 + scol, &Bs[(i * 256 + t) * 8]);
    __syncthreads();
#pragma unroll
    for (int kk = 0; kk < 2; ++kk) {
      short8 af[4], bfr[4];
#pragma unroll
      for (int m2 = 0; m2 < 4; ++m2)
        af[m2] = *(const short8*)&As[(wr * 64 + m2 * 16 + ll) * 64 + kk * 32 + lg * 8];
#pragma unroll
      for (int n2 = 0; n2 < 4; ++n2)
        bfr[n2] = *(const short8*)&Bs[(wc * 64 + n2 * 16 + ll) * 64 + kk * 32 + lg * 8];
#pragma unroll
      for (int m2 = 0; m2 < 4; ++m2)
#pragma unroll
        for (int n2 = 0; n2 < 4; ++n2)
          acc[m2][n2] =
              __builtin_amdgcn_mfma_f32_16x16x32_bf16(af[m2], bfr[n2], acc[m2][n2], 0, 0, 0);
    }
    __syncthreads();
  }
#pragma unroll
  for (int n2 = 0; n2 < 4; ++n2) {
    long cg = colTile + wc * 64 + n2 * 16 + ll;
    float bv = (cg < biasN) ? bias[cg] : 0.f;
#pragma unroll
    for (int m2 = 0; m2 < 4; ++m2) {
#pragma unroll
      for (int r = 0; r < 4; ++r) {
        long rg = rowTile + wr * 64 + m2 * 16 + lg * 4 + r;
        float v = acc[m2][n2][r] + bv;
        long idx = rg * ldc + cg;
        if (MODE == 0) {
          outb[idx] = f2bf(v);
        } else {
          int bb = (int)(rg >> 10);
          outf[idx] = xin[idx] + mods[(long)bb * MODS_LD + gateOff + cg] * v;
        }
      }
    }
  }
}

// ---------------- flash attention v2 -------------------------------------
// Pre-normed q/k; pre-transposed V (vt[(b,h), d, kv]). All LDS tiles staged
// via global_load_lds with inverse-swizzled source; reads XOR-swizzled
// (byte ^= (row&7)<<4). K/V double-buffered, one barrier per tile.
__global__ __launch_bounds__(256, 2) void attn_kernel(
    const u16* __restrict__ qb, int qStride, const u16* __restrict__ kb, int kvStride,
    const u16* __restrict__ vt, u16* __restrict__ outp, int Nk, int Mpb) {
  __shared__ u16 Qs[64 * 64];
  __shared__ u16 Ks[2][64 * 64];
  __shared__ u16 Vs[2][64 * 64];
  __shared__ u16 Ps[4][16 * 64];
  int t = threadIdx.x, w = t >> 6, l = t & 63;
  int qt = blockIdx.x, h = blockIdx.y, b = blockIdx.z;
  int lg = l >> 4, ll = l & 15;
  int rx = ll & 7;

  const u16* Qbase = qb + ((long)(b * NN + qt * 64)) * qStride + h * 64;
  const u16* Kbase = kb + ((long)b * Mpb) * kvStride + h * 64;
  const u16* Vbase = vt + ((long)(b * 16 + h) * 64) * 1024;

  int srow = t >> 3;
  int schunk = t & 7;

#pragma unroll
  for (int sh = 0; sh < 2; ++sh) {
    int row = sh * 32 + srow;
    int ck = schunk ^ (row & 7);
    gload_lds16(Qbase + (long)row * qStride + ck * 8, &Qs[sh * 2048 + t * 8]);
    gload_lds16(Kbase + (long)row * kvStride + ck * 8, &Ks[0][sh * 2048 + t * 8]);
    gload_lds16(Vbase + (long)row * 1024 + ck * 8, &Vs[0][sh * 2048 + t * 8]);
  }
  __syncthreads();

  short8 qf0 = *(const short8*)&Qs[(w * 16 + ll) * 64 + ((lg ^ rx) << 3)];
  short8 qf1 = *(const short8*)&Qs[(w * 16 + ll) * 64 + (((4 + lg) ^ rx) << 3)];

  float m[4], ssum[4];
  f32x4 o[4] = {};
#pragma unroll
  for (int r = 0; r < 4; ++r) { m[r] = -1e30f; ssum[r] = 0.f; }

  int nt = Nk >> 6;
  int cur = 0;
  for (int kt = 0; kt < nt; ++kt) {
    if (kt + 1 < nt) {  // issue next-tile DMA; completes by the end barrier
      const u16* kn = Kbase + (long)(kt + 1) * 64 * kvStride;
      const u16* vn = Vbase + (kt + 1) * 64;
#pragma unroll
      for (int sh = 0; sh < 2; ++sh) {
        int row = sh * 32 + srow;
        int ck = schunk ^ (row & 7);
        gload_lds16(kn + (long)row * kvStride + ck * 8, &Ks[cur ^ 1][sh * 2048 + t * 8]);
        gload_lds16(vn + (long)row * 1024 + ck * 8, &Vs[cur ^ 1][sh * 2048 + t * 8]);
      }
    }
    const u16* Kc = Ks[cur];
    f32x4 s[4] = {};
#pragma unroll
    for (int n = 0; n < 4; ++n) {
      short8 kf0 = *(const short8*)&Kc[(n * 16 + ll) * 64 + ((lg ^ rx) << 3)];
      short8 kf1 = *(const short8*)&Kc[(n * 16 + ll) * 64 + (((4 + lg) ^ rx) << 3)];
      s[n] = __builtin_amdgcn_mfma_f32_16x16x32_bf16(qf0, kf0, s[n], 0, 0, 0);
      s[n] = __builtin_amdgcn_mfma_f32_16x16x32_bf16(qf1, kf1, s[n], 0, 0, 0);
    }
    float p_[4][4];
#pragma unroll
    for (int r = 0; r < 4; ++r) {
      float pm = fmaxf(fmaxf(s[0][r], s[1][r]), fmaxf(s[2][r], s[3][r]));
      pm = fmaxf(pm, __shfl_xor(pm, 1));
      pm = fmaxf(pm, __shfl_xor(pm, 2));
      pm = fmaxf(pm, __shfl_xor(pm, 4));
      pm = fmaxf(pm, __shfl_xor(pm, 8));
      float nm = fmaxf(m[r], pm);
      float alpha = __expf(m[r] - nm);
      float rs = 0.f;
#pragma unroll
      for (int n = 0; n < 4; ++n) {
        float pv = __expf(s[n][r] - nm);
        p_[n][r] = pv;
        rs += pv;
      }
      rs += __shfl_xor(rs, 1);
      rs += __shfl_xor(rs, 2);
      rs += __shfl_xor(rs, 4);
      rs += __shfl_xor(rs, 8);
      ssum[r] = ssum[r] * alpha + rs;
      m[r] = nm;
#pragma unroll
      for (int n = 0; n < 4; ++n) o[n][r] *= alpha;
    }
    // P -> per-wave LDS (swizzled), reload as MFMA A-operand
#pragma unroll
    for (int n = 0; n < 4; ++n) {
      int chunk = n * 2 + (ll >> 3);
#pragma unroll
      for (int r = 0; r < 4; ++r) {
        int prow = lg * 4 + r;
        Ps[w][prow * 64 + (((chunk ^ (prow & 7)) << 3) | rx)] = f2bf(p_[n][r]);
      }
    }
    short8 pf0 = *(const short8*)&Ps[w][ll * 64 + ((lg ^ rx) << 3)];
    short8 pf1 = *(const short8*)&Ps[w][ll * 64 + (((4 + lg) ^ rx) << 3)];
    const u16* Vc = Vs[cur];
#pragma unroll
    for (int n = 0; n < 4; ++n) {
      short8 vf0 = *(const short8*)&Vc[(n * 16 + ll) * 64 + ((lg ^ rx) << 3)];
      short8 vf1 = *(const short8*)&Vc[(n * 16 + ll) * 64 + (((4 + lg) ^ rx) << 3)];
      o[n] = __builtin_amdgcn_mfma_f32_16x16x32_bf16(pf0, vf0, o[n], 0, 0, 0);
      o[n] = __builtin_amdgcn_mfma_f32_16x16x32_bf16(pf1, vf1, o[n], 0, 0, 0);
    }
    __syncthreads();
    cur ^= 1;
  }
#pragma unroll
  for (int n = 0; n < 4; ++n)
#pragma unroll
    for (int r = 0; r < 4; ++r) {
      long row = (long)b * NN + qt * 64 + w * 16 + lg * 4 + r;
      int col = h * 64 + n * 16 + ll;
      outp[row * DD + col] = f2bf(o[n][r] / ssum[r]);
    }
}

// ---------------- SwiGLU combine: h1 = silu(h1)*h2 ------------------------
__global__ void swiglu_kernel(u16* __restrict__ h1, const u16* __restrict__ h2, long n4) {
  long i = (long)blockIdx.x * 256 + threadIdx.x;
  if (i >= n4) return;
  ushort4 a = *(ushort4*)&h1[i * 4];
  ushort4 bq = *(const ushort4*)&h2[i * 4];
  u16 va[4] = {a.x, a.y, a.z, a.w}, vb[4] = {bq.x, bq.y, bq.z, bq.w};
  u16 oo[4];
#pragma unroll
  for (int j = 0; j < 4; ++j) {
    float f = bf2f(va[j]);
    float g = f / (1.f + __expf(-f));
    oo[j] = f2bf(g * bf2f(vb[j]));
  }
  ushort4 pk = {oo[0], oo[1], oo[2], oo[3]};
  *(ushort4*)&h1[i * 4] = pk;
}

extern "C" void kernel_launch(void* const* d_in, const int* in_sizes, int n_in,
                              void* d_out, int out_size, void* d_ws, size_t ws_size,
                              hipStream_t stream) {
  const float* x = (const float*)d_in[0];
  const float* src = (const float*)d_in[1];
  const float* c = (const float*)d_in[2];
  const float* ada_w = (const float*)d_in[3];
  const float* ada_b = (const float*)d_in[4];
  const float* n1_w = (const float*)d_in[5];
  const float* nc_w = (const float*)d_in[6];
  const float* n2_w = (const float*)d_in[7];
  const float* sa_qkv_w = (const float*)d_in[8];
  const float* sa_qkv_b = (const float*)d_in[9];
  const float* sa_qn_w = (const float*)d_in[10];
  const float* sa_kn_w = (const float*)d_in[11];
  const float* sa_o_w = (const float*)d_in[12];
  const float* sa_o_b = (const float*)d_in[13];
  const float* ca_q_w = (const float*)d_in[14];
  const float* ca_q_b = (const float*)d_in[15];
  const float* ca_kv_w = (const float*)d_in[16];
  const float* ca_kv_b = (const float*)d_in[17];
  const float* ca_qn_w = (const float*)d_in[18];
  const float* ca_kn_w = (const float*)d_in[19];
  const float* ca_o_w = (const float*)d_in[20];
  const float* ca_o_b = (const float*)d_in[21];
  const float* mlp_w1 = (const float*)d_in[22];
  const float* mlp_b1 = (const float*)d_in[23];
  const float* mlp_w2 = (const float*)d_in[24];
  const float* mlp_b2 = (const float*)d_in[25];
  const float* mlp_w3 = (const float*)d_in[26];
  const float* mlp_b3 = (const float*)d_in[27];
  float* out = (float*)d_out;

  char* p = (char*)d_ws;
  auto alloc = [&](size_t bytes) {
    char* r = p;
    p += (bytes + 255) & ~(size_t)255;
    return r;
  };
  float* mods = (float*)alloc(4l * 9216 * 4);
  float* sc = (float*)alloc(4096l * 4);
  float* part = (float*)alloc((long)MODS_KS * 4 * 9216 * 4);
  u16* qkvT = (u16*)alloc(3072l * 1024 * 2);
  u16* saoT = (u16*)alloc(1024l * 1024 * 2);
  u16* caqT = (u16*)alloc(1024l * 1024 * 2);
  u16* cakvT = (u16*)alloc(2048l * 1024 * 2);
  u16* caoT = (u16*)alloc(1024l * 1024 * 2);
  u16* w1T = (u16*)alloc(2816l * 1024 * 2);
  u16* w2T = (u16*)alloc(2816l * 1024 * 2);
  u16* w3T = (u16*)alloc(1024l * 2816 * 2);
  u16* xnb = (u16*)alloc(4096l * 1024 * 2);
  u16* srcb = (u16*)alloc(4096l * 1024 * 2);
  u16* bufA = (u16*)alloc(4096l * 3072 * 2);
  u16* bufB = (u16*)alloc(4096l * 2816 * 2);
  u16* attO = (u16*)alloc(4096l * 1024 * 2);
  u16* vtb = xnb;  // alias: xnb is dead during attention (qkv GEMM already consumed it)

  dim3 tb(32, 8);
  transpose_convert<<<dim3(32, 96), tb, 0, stream>>>(sa_qkv_w, qkvT, 1024, 3072, 1024, 3072);
  transpose_convert<<<dim3(32, 32), tb, 0, stream>>>(sa_o_w, saoT, 1024, 1024, 1024, 1024);
  transpose_convert<<<dim3(32, 32), tb, 0, stream>>>(ca_q_w, caqT, 1024, 1024, 1024, 1024);
  transpose_convert<<<dim3(32, 64), tb, 0, stream>>>(ca_kv_w, cakvT, 1024, 2048, 1024, 2048);
  transpose_convert<<<dim3(32, 32), tb, 0, stream>>>(ca_o_w, caoT, 1024, 1024, 1024, 1024);
  transpose_convert<<<dim3(32, 88), tb, 0, stream>>>(mlp_w1, w1T, 1024, 2730, 1024, 2816);
  transpose_convert<<<dim3(32, 88), tb, 0, stream>>>(mlp_w2, w2T, 1024, 2730, 1024, 2816);
  transpose_convert<<<dim3(88, 32), tb, 0, stream>>>(mlp_w3, w3T, 2730, 1024, 2816, 1024);
  cvt_bf16_kernel<<<4096, 256, 0, stream>>>(src, srcb, 4096l * 1024 / 4);
  silu_kernel<<<16, 256, 0, stream>>>(c, sc);
  mods_partial<<<dim3(36, MODS_KS), 256, 0, stream>>>(sc, ada_w, part);
  mods_reduce<<<dim3(36, 4), 256, 0, stream>>>(part, ada_b, mods);

  // ---- self-attention sublayer
  rmsmod_kernel<<<4096, 256, 0, stream>>>(x, n1_w, mods, 0, 1024, xnb);
  gemm_bf16<0><<<dim3(24, 32), 256, 0, stream>>>(xnb, qkvT, 1024, 3072, sa_qkv_b, 3072, bufA,
                                                 nullptr, nullptr, nullptr, 0);
  qknorm_kernel<<<4096, 256, 0, stream>>>(bufA, 3072, sa_qn_w, 0.125f);
  qknorm_kernel<<<4096, 256, 0, stream>>>(bufA + 1024, 3072, sa_kn_w, 1.0f);
  vtrans_kernel<<<dim3(16, 16, 4), 256, 0, stream>>>(bufA + 2048, 3072, 1024, vtb);
  attn_kernel<<<dim3(16, 16, 4), 256, 0, stream>>>(bufA, 3072, bufA + 1024, 3072, vtb, attO,
                                                   1024, 1024);
  gemm_bf16<1><<<dim3(8, 32), 256, 0, stream>>>(attO, saoT, 1024, 1024, sa_o_b, 1024, nullptr,
                                                out, x, mods, 2048);

  // ---- cross-attention sublayer
  rmsmod_kernel<<<4096, 256, 0, stream>>>(out, nc_w, mods, 3072, 4096, xnb);
  gemm_bf16<0><<<dim3(8, 32), 256, 0, stream>>>(xnb, caqT, 1024, 1024, ca_q_b, 1024, bufA,
                                                nullptr, nullptr, nullptr, 0);
  gemm_bf16<0><<<dim3(16, 32), 256, 0, stream>>>(srcb, cakvT, 1024, 2048, ca_kv_b, 2048, bufB,
                                                 nullptr, nullptr, nullptr, 0);
  qknorm_kernel<<<4096, 256, 0, stream>>>(bufA, 1024, ca_qn_w, 0.125f);
  qknorm_kernel<<<4096, 256, 0, stream>>>(bufB, 2048, ca_kn_w, 1.0f);
  vtrans_kernel<<<dim3(16, 16, 4), 256, 0, stream>>>(bufB + 1024, 2048, 1024, vtb);
  attn_kernel<<<dim3(16, 16, 4), 256, 0, stream>>>(bufA, 1024, bufB, 2048, vtb, attO, 1024,
                                                   1024);
  gemm_bf16<1><<<dim3(8, 32), 256, 0, stream>>>(attO, caoT, 1024, 1024, ca_o_b, 1024, nullptr,
                                                out, out, mods, 5120);

  // ---- SwiGLU FFN sublayer
  rmsmod_kernel<<<4096, 256, 0, stream>>>(out, n2_w, mods, 6144, 7168, xnb);
  gemm_bf16<0><<<dim3(22, 32), 256, 0, stream>>>(xnb, w1T, 1024, 2816, mlp_b1, 2730, bufA,
                                                 nullptr, nullptr, nullptr, 0);
  gemm_bf16<0><<<dim3(22, 32), 256, 0, stream>>>(xnb, w2T, 1024, 2816, mlp_b2, 2730, bufB,
                                                 nullptr, nullptr, nullptr, 0);
  swiglu_kernel<<<(int)((4096l * 2816 / 4 + 255) / 256), 256, 0, stream>>>(bufA, bufB,
                                                                           4096l * 2816 / 4);
  gemm_bf16<1><<<dim3(8, 32), 256, 0, stream>>>(bufA, w3T, 2816, 1024, mlp_b3, 1024, nullptr,
                                                out, out, mods, 8192);
}